// Round 1
// baseline (2397.965 us; speedup 1.0000x reference)
//
#include <hip/hip_runtime.h>

typedef _Float16 h2 __attribute__((ext_vector_type(2)));
typedef _Float16 h8 __attribute__((ext_vector_type(8)));

#define U_DIM 256
#define M_DIM 256
#define T_DIM 512

#if defined(__has_builtin)
#if __has_builtin(__builtin_amdgcn_fdot2)
#define HAVE_FDOT2 1
#endif
#endif

__device__ __forceinline__ float fdot2f(h2 a, h2 b, float c) {
#ifdef HAVE_FDOT2
  return __builtin_amdgcn_fdot2(a, b, c, false);
#else
  return fmaf((float)a[0], (float)b[0], fmaf((float)a[1], (float)b[1], c));
#endif
}

// ---------------- prep: pack recurrent weights to fp16 pairs ----------------
// Layout: w2[p*256 + j] = ( W[2p][j], W[2p+1][j] ), p in [0,128), j in [0,256)
__global__ void prep_w(const float* __restrict__ wuc, const float* __restrict__ wrc,
                       const float* __restrict__ wcc,
                       h2* __restrict__ wu2, h2* __restrict__ wr2, h2* __restrict__ wc2) {
  int idx = blockIdx.x * 256 + threadIdx.x;   // 0..32767
  int p = idx >> 8, j = idx & 255;
  int k0 = (2 * p) * U_DIM + j;
  int k1 = (2 * p + 1) * U_DIM + j;
  wu2[idx] = h2{(_Float16)wuc[k0], (_Float16)wuc[k1]};
  wr2[idx] = h2{(_Float16)wrc[k0], (_Float16)wrc[k1]};
  wc2[idx] = h2{(_Float16)wcc[k0], (_Float16)wcc[k1]};
}

// ---------------- xproj GEMM (fp32): out[r][j] = x_row(r) . W[:,j] ----------
// r = m*len + tc maps to x row (m*512 + t0 + tc). Tile 128x128, 256 thr, 8x8 micro.
#define TR 128
#define TCOL 128
#define KS 16

__global__ __launch_bounds__(256, 2)
void xproj_gemm(const float* __restrict__ x,
                const float* __restrict__ Wu, const float* __restrict__ Wr,
                const float* __restrict__ Wc,
                const float* __restrict__ Bu, const float* __restrict__ Br,
                const float* __restrict__ Bc,
                float* __restrict__ XU, float* __restrict__ XR, float* __restrict__ XC,
                int t0, int len) {
  const float* W; const float* B; float* O;
  if (blockIdx.z == 0)      { W = Wu; B = Bu; O = XU; }
  else if (blockIdx.z == 1) { W = Wr; B = Br; O = XR; }
  else                      { W = Wc; B = Bc; O = XC; }

  __shared__ float a_sh[KS][TR + 4];    // [k][row], pad keeps reads conflict-free
  __shared__ float b_sh[KS][TCOL + 4];  // [k][col]

  const int tid = threadIdx.x;
  const int tx = tid & 15, ty = tid >> 4;
  const int r0 = blockIdx.x * TR;
  const int c0 = blockIdx.y * TCOL;

  // A staging: thread loads 2 float4 of row (tid>>1), k-offsets ak0, ak0+4
  const int arow = tid >> 1;
  const int ak0  = (tid & 1) * 8;
  const int r    = r0 + arow;
  const int mm   = r / len;
  const int tc   = r - mm * len;
  const float* xrow = x + ((size_t)mm * T_DIM + (size_t)(t0 + tc)) * U_DIM;

  // B staging: thread loads 2 float4 of k-row (tid>>4), col-offsets bc0, bc0+4
  const int bkr = tid >> 4;
  const int bc0 = (tid & 15) * 8;

  float acc[8][8];
#pragma unroll
  for (int i = 0; i < 8; ++i)
#pragma unroll
    for (int q = 0; q < 8; ++q) acc[i][q] = 0.f;

  for (int kk = 0; kk < U_DIM; kk += KS) {
    float4 va0 = *(const float4*)(xrow + kk + ak0);
    float4 va1 = *(const float4*)(xrow + kk + ak0 + 4);
    float4 wb0 = *(const float4*)(W + (size_t)(kk + bkr) * U_DIM + c0 + bc0);
    float4 wb1 = *(const float4*)(W + (size_t)(kk + bkr) * U_DIM + c0 + bc0 + 4);
    __syncthreads();  // previous compute done before overwriting LDS
    a_sh[ak0 + 0][arow] = va0.x; a_sh[ak0 + 1][arow] = va0.y;
    a_sh[ak0 + 2][arow] = va0.z; a_sh[ak0 + 3][arow] = va0.w;
    a_sh[ak0 + 4][arow] = va1.x; a_sh[ak0 + 5][arow] = va1.y;
    a_sh[ak0 + 6][arow] = va1.z; a_sh[ak0 + 7][arow] = va1.w;
    *(float4*)&b_sh[bkr][bc0]     = wb0;
    *(float4*)&b_sh[bkr][bc0 + 4] = wb1;
    __syncthreads();
#pragma unroll
    for (int k = 0; k < KS; ++k) {
      float4 av0 = *(const float4*)&a_sh[k][ty * 8];
      float4 av1 = *(const float4*)&a_sh[k][ty * 8 + 4];
      float4 bv0 = *(const float4*)&b_sh[k][tx * 8];
      float4 bv1 = *(const float4*)&b_sh[k][tx * 8 + 4];
      float aa[8] = {av0.x, av0.y, av0.z, av0.w, av1.x, av1.y, av1.z, av1.w};
      float bb[8] = {bv0.x, bv0.y, bv0.z, bv0.w, bv1.x, bv1.y, bv1.z, bv1.w};
#pragma unroll
      for (int i = 0; i < 8; ++i)
#pragma unroll
        for (int q = 0; q < 8; ++q)
          acc[i][q] = fmaf(aa[i], bb[q], acc[i][q]);
    }
  }

  float4 bi0 = *(const float4*)(B + c0 + tx * 8);
  float4 bi1 = *(const float4*)(B + c0 + tx * 8 + 4);
  float bb2[8] = {bi0.x, bi0.y, bi0.z, bi0.w, bi1.x, bi1.y, bi1.z, bi1.w};
#pragma unroll
  for (int i = 0; i < 8; ++i) {
    int rr = r0 + ty * 8 + i;
    float4 o0 = {acc[i][0] + bb2[0], acc[i][1] + bb2[1], acc[i][2] + bb2[2], acc[i][3] + bb2[3]};
    float4 o1 = {acc[i][4] + bb2[4], acc[i][5] + bb2[5], acc[i][6] + bb2[6], acc[i][7] + bb2[7]};
    *(float4*)(O + (size_t)rr * U_DIM + c0 + tx * 8)     = o0;
    *(float4*)(O + (size_t)rr * U_DIM + c0 + tx * 8 + 4) = o1;
  }
}

// ---------------- recurrence: 1 WG per batch row, thread j owns unit j ------
// Weights resident in VGPRs as packed fp16 (384 regs); c/h as fp16 in LDS.
__global__ __launch_bounds__(256, 1)
void gru_rec(const float* __restrict__ XU, const float* __restrict__ XR,
             const float* __restrict__ XC,
             const h2* __restrict__ wu2, const h2* __restrict__ wr2,
             const h2* __restrict__ wc2,
             const float* __restrict__ c_in, float* __restrict__ c_out, int len) {
  const int m = blockIdx.x;
  const int j = threadIdx.x;

  __shared__ h8 ch8[32];  // c as fp16, 256 values
  __shared__ h8 hh8[32];  // (g_r * c) as fp16

  h2 WU[128], WR[128], WC[128];
#pragma unroll
  for (int p = 0; p < 128; ++p) {
    WU[p] = wu2[p * U_DIM + j];
    WR[p] = wr2[p * U_DIM + j];
    WC[p] = wc2[p * U_DIM + j];
  }

  float cj = c_in[m * U_DIM + j];
  ((_Float16*)ch8)[j] = (_Float16)cj;

  const float* xu = XU + (size_t)m * len * U_DIM + j;
  const float* xr = XR + (size_t)m * len * U_DIM + j;
  const float* xc = XC + (size_t)m * len * U_DIM + j;

  __syncthreads();

  for (int t = 0; t < len; ++t) {
    float xuv = xu[t * U_DIM];
    float xrv = xr[t * U_DIM];
    float xcv = xc[t * U_DIM];

    float pu = 0.f, pr = 0.f;
#pragma unroll
    for (int p = 0; p < 32; ++p) {
      h8 cv = ch8[p];  // broadcast ds_read_b128
#pragma unroll
      for (int q = 0; q < 4; ++q) {
        h2 cp = {cv[2 * q], cv[2 * q + 1]};
        pu = fdot2f(cp, WU[4 * p + q], pu);
        pr = fdot2f(cp, WR[4 * p + q], pr);
      }
    }
    float gu = 1.f / (1.f + expf(-(pu + xuv)));
    float gr = 1.f / (1.f + expf(-(pr + xrv)));
    ((_Float16*)hh8)[j] = (_Float16)(gr * cj);
    __syncthreads();

    float pc = 0.f;
#pragma unroll
    for (int p = 0; p < 32; ++p) {
      h8 hv = hh8[p];
#pragma unroll
      for (int q = 0; q < 4; ++q) {
        h2 hp = {hv[2 * q], hv[2 * q + 1]};
        pc = fdot2f(hp, WC[4 * p + q], pc);
      }
    }
    float cand = tanhf(pc + xcv);
    cj = fmaf(gu, cand - cj, cj);  // gu*cand + (1-gu)*cj
    ((_Float16*)ch8)[j] = (_Float16)cj;
    __syncthreads();
  }

  c_out[m * U_DIM + j] = cj;
}

// ---------------- host ------------------------------------------------------
extern "C" void kernel_launch(void* const* d_in, const int* in_sizes, int n_in,
                              void* d_out, int out_size, void* d_ws, size_t ws_size,
                              hipStream_t stream) {
  const float* x   = (const float*)d_in[0];
  const float* a0  = (const float*)d_in[1];
  const float* wcx = (const float*)d_in[2];
  const float* wcc = (const float*)d_in[3];
  const float* bc  = (const float*)d_in[4];
  const float* wux = (const float*)d_in[5];
  const float* wuc = (const float*)d_in[6];
  const float* bu  = (const float*)d_in[7];
  const float* wrx = (const float*)d_in[8];
  const float* wrc = (const float*)d_in[9];
  const float* br  = (const float*)d_in[10];
  float* out = (float*)d_out;

  const size_t W16_BYTES = 3ull * 128 * 256 * sizeof(h2);  // 393216
  size_t avail = (ws_size > W16_BYTES) ? (ws_size - W16_BYTES) : 0;
  const size_t perT = 3ull * M_DIM * U_DIM * sizeof(float);  // bytes per timestep of xproj
  int Tc = (int)(avail / perT);
  if (Tc > T_DIM) Tc = T_DIM;
  if (Tc < 1) Tc = 1;
  int nch = (T_DIM + Tc - 1) / Tc;
  Tc = (T_DIM + nch - 1) / nch;  // balance chunk sizes

  float* XU = (float*)d_ws;
  float* XR = XU + (size_t)M_DIM * Tc * U_DIM;
  float* XC = XR + (size_t)M_DIM * Tc * U_DIM;
  h2* W16 = (h2*)(XC + (size_t)M_DIM * Tc * U_DIM);
  h2* wu2 = W16;
  h2* wr2 = W16 + 32768;
  h2* wc2 = W16 + 65536;

  prep_w<<<128, 256, 0, stream>>>(wuc, wrc, wcc, wu2, wr2, wc2);

  for (int t0 = 0; t0 < T_DIM; t0 += Tc) {
    int lenc = (T_DIM - t0) < Tc ? (T_DIM - t0) : Tc;
    dim3 g((M_DIM * lenc) / TR, U_DIM / TCOL, 3);
    xproj_gemm<<<g, 256, 0, stream>>>(x, wux, wrx, wcx, bu, br, bc,
                                      XU, XR, XC, t0, lenc);
    gru_rec<<<M_DIM, 256, 0, stream>>>(XU, XR, XC, wu2, wr2, wc2,
                                       (t0 == 0 ? a0 : out), out, lenc);
  }
}